// Round 4
// baseline (586.613 us; speedup 1.0000x reference)
//
#include <hip/hip_runtime.h>
#include <stdint.h>
#include <math.h>

#pragma clang fp contract(off)

#define NB 4
#define NN 1024
#define KNN 20
#define NT 10

// ---------------------------------------------------------------------------
// Graph build
// ---------------------------------------------------------------------------
__global__ __launch_bounds__(256) void graph_kernel(const float* __restrict__ pc,
        int* __restrict__ idx_out, float* __restrict__ w_out, float* __restrict__ s_out){
  int row = blockIdx.x;              // b*NN + i
  int b = row >> 10, i = row & (NN-1);
  int tid = threadIdx.x;
  __shared__ float d2s[NN];
  __shared__ unsigned long long red[256];
  __shared__ int   sel_idx[KNN];
  __shared__ float sel_d2[KNN];
  const float* pb = pc + (size_t)b*NN*3;
  float xi = pb[i*3+0], yi = pb[i*3+1], zi = pb[i*3+2];
  for (int j=tid; j<NN; j+=256){
    float dx = xi - pb[j*3+0];
    float dy = yi - pb[j*3+1];
    float dz = zi - pb[j*3+2];
    float d2 = dx*dx;
    d2 = d2 + dy*dy;
    d2 = d2 + dz*dz;
    if (j==i) d2 = d2 + 1e9f;
    d2s[j] = d2;
  }
  __syncthreads();
  for (int k=0;k<KNN;k++){
    unsigned long long best = 0xffffffffffffffffull;
    for (int j=tid;j<NN;j+=256){
      unsigned long long key = ((unsigned long long)__float_as_uint(d2s[j])<<32) | (unsigned int)j;
      if (key < best) best = key;
    }
    red[tid] = best;
    __syncthreads();
    for (int off=128; off>0; off>>=1){
      if (tid < off){ if (red[tid+off] < red[tid]) red[tid] = red[tid+off]; }
      __syncthreads();
    }
    if (tid==0){
      unsigned long long bk = red[0];
      int bj = (int)(bk & 0xffffffffu);
      sel_idx[k] = bj;
      sel_d2[k]  = __uint_as_float((unsigned int)(bk >> 32));
      d2s[bj] = __uint_as_float(0x7f800000u);
    }
    __syncthreads();
  }
  if (tid==0){
    float dist[KNN]; float dsum = 0.0f;
    for (int k=0;k<KNN;k++){ dist[k] = sqrtf(fmaxf(sel_d2[k], 1e-12f)); dsum = dsum + dist[k]; }
    float sigma = dsum / 20.0f;
    sigma = 1.0f * sigma + 1e-6f;
    float s2 = sigma * sigma;
    float wv[KNN]; float wsum = 0.0f;
    for (int k=0;k<KNN;k++){
      float ds = dist[k]*dist[k];
      wv[k] = expf((-ds)/s2);
      wsum = wsum + wv[k];
    }
    float denom = wsum + 1e-6f;
    for (int k=0;k<KNN;k++){
      w_out[(size_t)row*KNN+k]  = wv[k] / denom;
      idx_out[(size_t)row*KNN+k] = sel_idx[k];
    }
    s_out[row] = 1.0f * sigma;
  }
}

// ---------------------------------------------------------------------------
// Encoder
// ---------------------------------------------------------------------------
__global__ void enc_kernel(const float* __restrict__ pc, const float* __restrict__ W,
                           const float* __restrict__ bias, float* __restrict__ rates){
  int id = blockIdx.x*blockDim.x + threadIdx.x;
  if (id >= NB*NN*64) return;
  int f = id & 63; int bn = id >> 6;
  float p0 = pc[bn*3+0], p1 = pc[bn*3+1], p2 = pc[bn*3+2];
  float acc = fmaf(p0, W[0*64+f], 0.0f);
  acc = fmaf(p1, W[1*64+f], acc);
  acc = fmaf(p2, W[2*64+f], acc);
  acc = acc + bias[f];
  acc = fmaxf(acc, 0.0f);
  acc = fminf(fmaxf(acc, 0.0f), 1.0f);
  rates[id] = acc;
}

// ---------------------------------------------------------------------------
// Poisson encoding (JAX threefry2x32, key (0,42))
// ---------------------------------------------------------------------------
__device__ __forceinline__ uint32_t rotl32(uint32_t x, uint32_t r){ return (x<<r) | (x>>(32u-r)); }

__global__ void poisson_kernel(const float* __restrict__ rates, uint8_t* __restrict__ out){
  const uint32_t H = (uint32_t)(NB*NT*NN*64) / 2u;
  uint32_t i = blockIdx.x*blockDim.x + threadIdx.x;
  if (i >= H) return;
  const uint32_t ks0 = 0u, ks1 = 42u;
  const uint32_t ks2 = ks0 ^ ks1 ^ 0x1BD11BDAu;
  uint32_t x0 = i + ks0;
  uint32_t x1 = (i + H) + ks1;
#define TF4(a,b,c,d) \
  x0 += x1; x1 = rotl32(x1,a); x1 ^= x0; \
  x0 += x1; x1 = rotl32(x1,b); x1 ^= x0; \
  x0 += x1; x1 = rotl32(x1,c); x1 ^= x0; \
  x0 += x1; x1 = rotl32(x1,d); x1 ^= x0;
  TF4(13u,15u,26u,6u)  x0 += ks1; x1 += ks2 + 1u;
  TF4(17u,29u,16u,24u) x0 += ks2; x1 += ks0 + 2u;
  TF4(13u,15u,26u,6u)  x0 += ks0; x1 += ks1 + 3u;
  TF4(17u,29u,16u,24u) x0 += ks1; x1 += ks2 + 4u;
  TF4(13u,15u,26u,6u)  x0 += ks2; x1 += ks0 + 5u;
#undef TF4
  {
    uint32_t m = i;
    float u = __uint_as_float((x0 >> 9) | 0x3f800000u) - 1.0f;
    uint32_t f = m & 63u, n = (m >> 6) & (NN-1);
    uint32_t bt = m >> 16; uint32_t b = bt / NT;
    float rate = rates[(((size_t)b<<10) + n)*64 + f];
    out[m] = (u < rate) ? (uint8_t)1 : (uint8_t)0;
  }
  {
    uint32_t m = i + H;
    float u = __uint_as_float((x1 >> 9) | 0x3f800000u) - 1.0f;
    uint32_t f = m & 63u, n = (m >> 6) & (NN-1);
    uint32_t bt = m >> 16; uint32_t b = bt / NT;
    float rate = rates[(((size_t)b<<10) + n)*64 + f];
    out[m] = (u < rate) ? (uint8_t)1 : (uint8_t)0;
  }
}

// ---------------------------------------------------------------------------
// lap1: t1 = s*(x - sum_k w_k x[idx_k]); 256-thread blocks, R=256/F rows each
// ---------------------------------------------------------------------------
template<int F>
__global__ __launch_bounds__(256) void lap1_kernel2(const uint8_t* __restrict__ x,
        const int* __restrict__ idx, const float* __restrict__ w, const float* __restrict__ s,
        float* __restrict__ t1, int t0){
  constexpr int R = 256 / F;
  int tid = threadIdx.x;
  int rsub = tid / F;
  int f = tid % F;
  int row = blockIdx.x * R + rsub;          // over M = NB*NN*tc
  int bn = row % (NB*NN); int tt = row / (NB*NN);
  int b = bn >> 10; int n = bn & (NN-1); int t = t0 + tt;
  __shared__ int   nidx[R][KNN];
  __shared__ float nw[R][KNN];
  __shared__ float sv[R];
  if (f < KNN){ nidx[rsub][f] = idx[(size_t)bn*KNN+f]; nw[rsub][f] = w[(size_t)bn*KNN+f]; }
  if (f == 0) sv[rsub] = s[bn];
  __syncthreads();
  const uint8_t* xb = x + ((size_t)(b*NT + t)*NN)*F;
  float acc = 0.0f;
  for (int k=0;k<KNN;k++)
    acc = fmaf(nw[rsub][k], (float)xb[(size_t)nidx[rsub][k]*F + f], acc);
  float xv = (float)xb[(size_t)n*F + f];
  t1[(size_t)row*F + f] = sv[rsub] * (xv - acc);
}

// ---------------------------------------------------------------------------
// lap2: t2 = 2*(s*(t1 - sum_k w_k t1[idx_k])) - x
// ---------------------------------------------------------------------------
template<int F>
__global__ __launch_bounds__(256) void lap2_kernel2(const uint8_t* __restrict__ x,
        const float* __restrict__ t1, const int* __restrict__ idx, const float* __restrict__ w,
        const float* __restrict__ s, float* __restrict__ t2, int t0){
  constexpr int R = 256 / F;
  int tid = threadIdx.x;
  int rsub = tid / F;
  int f = tid % F;
  int row = blockIdx.x * R + rsub;
  int bn = row % (NB*NN); int tt = row / (NB*NN);
  int b = bn >> 10; int n = bn & (NN-1); int t = t0 + tt;
  __shared__ int   nidx[R][KNN];
  __shared__ float nw[R][KNN];
  __shared__ float sv[R];
  if (f < KNN){ nidx[rsub][f] = idx[(size_t)bn*KNN+f]; nw[rsub][f] = w[(size_t)bn*KNN+f]; }
  if (f == 0) sv[rsub] = s[bn];
  __syncthreads();
  const float* t1b = t1 + ((size_t)tt*(NB*NN) + (size_t)b*NN)*F;
  float acc = 0.0f;
  for (int k=0;k<KNN;k++)
    acc = fmaf(nw[rsub][k], t1b[(size_t)nidx[rsub][k]*F + f], acc);
  float tv = t1[(size_t)row*F + f];
  float lapv = sv[rsub] * (tv - acc);
  const uint8_t* xb = x + ((size_t)(b*NT + t)*NN)*F;
  float xv = (float)xb[(size_t)n*F + f];
  t2[(size_t)row*F + f] = 2.0f * lapv - xv;
}

// ---------------------------------------------------------------------------
// Chebyshev conv GEMM v2: BM=128, BK=16, TM=8, TN split into two half-tiles
// so all LDS reads are broadcast/2-way (conflict-free). k-chain order is
// unchanged (s-major, f ascending) -> bit-identical outputs.
// ---------------------------------------------------------------------------
template<int F, int G, int BN, int TN>
__global__ __launch_bounds__(256) void conv_gemm2_kernel(const uint8_t* __restrict__ x,
        const float* __restrict__ t1, const float* __restrict__ t2,
        const float* __restrict__ W, float* __restrict__ abuf, int t0){
  constexpr int BM = 128, BK = 16, TM = 8;
  constexpr int NTX = BN / TN;               // 16
  constexpr int NTY = 256 / NTX;             // 16
  static_assert(NTY * TM == BM, "tile mismatch");
  constexpr int TNH = TN / 2;
  constexpr int LDA = BM + 4;                // 132
  constexpr int LDB = BN + 4;
  __shared__ float As[BK * LDA];
  __shared__ float Ws[BK * LDB];

  const int tid = threadIdx.x;
  const int tx = tid % NTX, ty = tid / NTX;
  const int row0 = blockIdx.x * BM;
  const int g0 = blockIdx.y * BN;

  // A-load mapping: each thread loads 8 consecutive k (two float4) for one row
  const int arow = tid >> 1;                 // 0..127
  const int akg  = (tid & 1) * 8;            // 0 or 8
  const int grow = row0 + arow;
  const int bn_a = grow % (NB*NN);
  const int tt_a = grow / (NB*NN);
  const int b_a = bn_a >> 10, n_a = bn_a & (NN-1);
  const uint8_t* xrow  = x  + ((size_t)(b_a*NT + t0 + tt_a)*NN + n_a)*F;
  const float*   t1row = t1 + (size_t)grow * F;
  const float*   t2row = t2 + (size_t)grow * F;

  float acc[TM][TN];
  #pragma unroll
  for (int r=0;r<TM;r++)
    #pragma unroll
    for (int c=0;c<TN;c++) acc[r][c] = 0.0f;

  for (int s = 0; s < 3; ++s){
    for (int f0 = 0; f0 < F; f0 += BK){
      // --- stage A chunk: rows of [x|t1|t2] ---
      if (s == 0){
        uchar4 u0 = *(const uchar4*)(xrow + f0 + akg);
        uchar4 u1 = *(const uchar4*)(xrow + f0 + akg + 4);
        As[(akg+0)*LDA + arow] = (float)u0.x;
        As[(akg+1)*LDA + arow] = (float)u0.y;
        As[(akg+2)*LDA + arow] = (float)u0.z;
        As[(akg+3)*LDA + arow] = (float)u0.w;
        As[(akg+4)*LDA + arow] = (float)u1.x;
        As[(akg+5)*LDA + arow] = (float)u1.y;
        As[(akg+6)*LDA + arow] = (float)u1.z;
        As[(akg+7)*LDA + arow] = (float)u1.w;
      } else {
        const float* src = ((s==1) ? t1row : t2row) + f0 + akg;
        float4 v0 = *(const float4*)src;
        float4 v1 = *(const float4*)(src + 4);
        As[(akg+0)*LDA + arow] = v0.x;
        As[(akg+1)*LDA + arow] = v0.y;
        As[(akg+2)*LDA + arow] = v0.z;
        As[(akg+3)*LDA + arow] = v0.w;
        As[(akg+4)*LDA + arow] = v1.x;
        As[(akg+5)*LDA + arow] = v1.y;
        As[(akg+6)*LDA + arow] = v1.z;
        As[(akg+7)*LDA + arow] = v1.w;
      }
      // --- stage W chunk ---
      const float* Wsrc = W + ((size_t)(s*F + f0))*G + g0;
      #pragma unroll
      for (int e = 0; e < (BK*BN)/(256*4); ++e){
        int idx2 = tid + e*256;
        int wk = idx2 / (BN/4);
        int wg = (idx2 % (BN/4))*4;
        *(float4*)&Ws[wk*LDB + wg] = *(const float4*)(Wsrc + (size_t)wk*G + wg);
      }
      __syncthreads();
      // --- compute ---
      #pragma unroll
      for (int k = 0; k < BK; ++k){
        float a[TM];
        *(float4*)&a[0] = *(const float4*)&As[k*LDA + ty*4];
        *(float4*)&a[4] = *(const float4*)&As[k*LDA + BM/2 + ty*4];
        float wv[TN];
        if constexpr (TN == 8){
          *(float4*)&wv[0] = *(const float4*)&Ws[k*LDB + tx*4];
          *(float4*)&wv[4] = *(const float4*)&Ws[k*LDB + BN/2 + tx*4];
        } else {
          *(float2*)&wv[0] = *(const float2*)&Ws[k*LDB + tx*2];
          *(float2*)&wv[2] = *(const float2*)&Ws[k*LDB + BN/2 + tx*2];
        }
        #pragma unroll
        for (int r=0;r<TM;r++)
          #pragma unroll
          for (int c=0;c<TN;c++)
            acc[r][c] = fmaf(a[r], wv[c], acc[r][c]);
      }
      __syncthreads();
    }
  }
  // epilogue: raw GEMM result (bias added in LIF, preserving order)
  #pragma unroll
  for (int rg=0; rg<2; ++rg){
    #pragma unroll
    for (int r=0; r<TM/2; ++r){
      float* dst = abuf + (size_t)(row0 + rg*(BM/2) + ty*(TM/2) + r)*G + g0;
      if constexpr (TN == 8){
        *(float4*)(dst + tx*4)        = *(float4*)&acc[rg*(TM/2)+r][0];
        *(float4*)(dst + BN/2 + tx*4) = *(float4*)&acc[rg*(TM/2)+r][4];
      } else {
        *(float2*)(dst + tx*2)        = *(float2*)&acc[rg*(TM/2)+r][0];
        *(float2*)(dst + BN/2 + tx*2) = *(float2*)&acc[rg*(TM/2)+r][2];
      }
    }
  }
}

// ---------------------------------------------------------------------------
// LIF scan: bias added here in reference order: a = gemm + b; v = decay*v + a
// ---------------------------------------------------------------------------
__global__ void lif_kernel(const float* __restrict__ abuf, const float* __restrict__ bias,
        float* __restrict__ vbuf, uint8_t* __restrict__ out, int t0, int tc, int G, float decay){
  int id = blockIdx.x*blockDim.x + threadIdx.x;
  if (id >= NB*NN*G) return;
  int g = id % G;
  int bn = id / G;
  int b = bn >> 10, n = bn & (NN-1);
  float v = (t0 == 0) ? 0.0f : vbuf[id];
  float bg = bias[g];
  for (int tt=0; tt<tc; ++tt){
    float a = abuf[((size_t)tt*(NB*NN) + bn)*G + g] + bg;
    float vn = decay * v + a;
    float sp  = ((vn - 1.0f) >= 0.0f) ? 1.0f : 0.0f;
    float snk = ((-1.0f - vn) >= 0.0f) ? 1.0f : 0.0f;
    vn = vn - sp * 1.0f;
    vn = vn - snk * (-1.0f);
    v = vn;
    uint8_t* ob = out + ((size_t)(b*NT + t0 + tt)*NN + n)*((size_t)2*G);
    ob[g]   = (uint8_t)sp;
    ob[G+g] = (uint8_t)snk;
  }
  if (t0 + tc < NT) vbuf[id] = v;
}

// ---------------------------------------------------------------------------
// Pool stage 1: integer spike counts (exact, order-independent)
// ---------------------------------------------------------------------------
__global__ void pool_partial_kernel(const uint8_t* __restrict__ sp, uint32_t* __restrict__ partial){
  int b = blockIdx.x >> 6;
  int chunk = blockIdx.x & 63;
  int n0 = chunk * 16;
  int u = threadIdx.x;                      // 0..127
  uint32_t c0=0,c1=0,c2=0,c3=0;
  for (int t=0;t<NT;t++){
    for (int n=0;n<16;n++){
      const uint32_t* rowp = (const uint32_t*)(sp + ((size_t)(b*NT+t)*NN + n0+n)*512);
      uint32_t wv = rowp[u];
      c0 += wv & 0xffu;
      c1 += (wv >> 8) & 0xffu;
      c2 += (wv >> 16) & 0xffu;
      c3 += wv >> 24;
    }
  }
  uint32_t* op = partial + (size_t)blockIdx.x*512 + u*4;
  op[0]=c0; op[1]=c1; op[2]=c2; op[3]=c3;
}

__global__ __launch_bounds__(512) void finalize_head_kernel(const uint32_t* __restrict__ partial,
        const float* __restrict__ roW, const float* __restrict__ rob, float* __restrict__ out){
  int b = blockIdx.x;
  int f = threadIdx.x;
  __shared__ float pooled[512];
  uint32_t cnt = 0;
  for (int ch=0; ch<64; ch++)
    cnt += partial[((size_t)(b*64+ch))*512 + f];
  pooled[f] = (float)cnt / 10.0f / 1024.0f;
  __syncthreads();
  if (f < 40){
    float acc = 0.0f;
    for (int k=0;k<512;k++)
      acc = fmaf(pooled[k], roW[k*40+f], acc);
    out[b*40 + f] = acc + rob[f];
  }
}

// ---------------------------------------------------------------------------
extern "C" void kernel_launch(void* const* d_in, const int* in_sizes, int n_in,
                              void* d_out, int out_size, void* d_ws, size_t ws_size,
                              hipStream_t stream) {
  const float* pc   = (const float*)d_in[0];
  const float* encW = (const float*)d_in[1];
  const float* encB = (const float*)d_in[2];
  const float* W0   = (const float*)d_in[3];
  const float* b0   = (const float*)d_in[4];
  const float* W1   = (const float*)d_in[5];
  const float* b1   = (const float*)d_in[6];
  const float* W2   = (const float*)d_in[7];
  const float* b2   = (const float*)d_in[8];
  const float* roW  = (const float*)d_in[9];
  const float* rob  = (const float*)d_in[10];
  float* outp = (float*)d_out;

  char* p = (char*)d_ws;
  auto alloc = [&](size_t bytes)->char*{
    char* r = p; p += (bytes + 255) & ~(size_t)255; return r;
  };
  int*      idxb   = (int*)     alloc((size_t)NB*NN*KNN*4);
  float*    wb     = (float*)   alloc((size_t)NB*NN*KNN*4);
  float*    sb     = (float*)   alloc((size_t)NB*NN*4);
  float*    rates  = (float*)   alloc((size_t)NB*NN*64*4);
  float*    vbuf   = (float*)   alloc((size_t)NB*NN*256*4);
  uint32_t* partial= (uint32_t*)alloc((size_t)NB*64*512*4);
  uint8_t*  bufA   = (uint8_t*) alloc((size_t)NB*NT*NN*512);
  uint8_t*  bufB   = (uint8_t*) alloc((size_t)NB*NT*NN*512);

  // timestep chunking: t1 + t2 + abuf per timestep (worst case F=256)
  size_t used = (size_t)(p - (char*)d_ws);
  size_t per_t = (size_t)NB*NN*256*4*3;
  int TC = 1;
  if (ws_size > used + per_t){
    size_t tcc = (ws_size - used) / per_t;
    TC = (tcc >= NT) ? NT : (int)tcc;
    if (TC < 1) TC = 1;
  }
  float* t1b  = (float*)alloc((size_t)NB*(size_t)TC*NN*256*4);
  float* t2b  = (float*)alloc((size_t)NB*(size_t)TC*NN*256*4);
  float* abuf = (float*)alloc((size_t)NB*(size_t)TC*NN*256*4);

  graph_kernel<<<NB*NN, 256, 0, stream>>>(pc, idxb, wb, sb);
  enc_kernel<<<(NB*NN*64 + 255)/256, 256, 0, stream>>>(pc, encW, encB, rates);
  {
    const uint32_t H = (uint32_t)(NB*NT*NN*64) / 2u;
    poisson_kernel<<<(H + 255)/256, 256, 0, stream>>>(rates, bufA);
  }

  float decay = expf(-1.0f / 20.0f);

  uint8_t* xin  = bufA;
  uint8_t* xout = bufB;
  for (int l=0; l<3; l++){
    int G = (l==0)?64:(l==1)?128:256;
    const float* Wc = (l==0)?W0:(l==1)?W1:W2;
    const float* bc = (l==0)?b0:(l==1)?b1:b2;
    for (int t0=0; t0<NT; t0+=TC){
      int tc = (NT - t0 < TC) ? (NT - t0) : TC;
      int M = NB*NN*tc;
      if (l==0){
        lap1_kernel2<64><<<M/4, 256, 0, stream>>>(xin, idxb, wb, sb, t1b, t0);
        lap2_kernel2<64><<<M/4, 256, 0, stream>>>(xin, t1b, idxb, wb, sb, t2b, t0);
        dim3 grid(M/128, 1);
        conv_gemm2_kernel<64,64,64,4><<<grid, 256, 0, stream>>>(xin, t1b, t2b, Wc, abuf, t0);
      } else if (l==1){
        lap1_kernel2<128><<<M/2, 256, 0, stream>>>(xin, idxb, wb, sb, t1b, t0);
        lap2_kernel2<128><<<M/2, 256, 0, stream>>>(xin, t1b, idxb, wb, sb, t2b, t0);
        dim3 grid(M/128, 1);
        conv_gemm2_kernel<128,128,128,8><<<grid, 256, 0, stream>>>(xin, t1b, t2b, Wc, abuf, t0);
      } else {
        lap1_kernel2<256><<<M, 256, 0, stream>>>(xin, idxb, wb, sb, t1b, t0);
        lap2_kernel2<256><<<M, 256, 0, stream>>>(xin, t1b, idxb, wb, sb, t2b, t0);
        dim3 grid(M/128, 2);
        conv_gemm2_kernel<256,256,128,8><<<grid, 256, 0, stream>>>(xin, t1b, t2b, Wc, abuf, t0);
      }
      lif_kernel<<<(NB*NN*G + 255)/256, 256, 0, stream>>>(abuf, bc, vbuf, xout, t0, tc, G, decay);
    }
    uint8_t* tmp = xin; xin = xout; xout = tmp;
  }

  pool_partial_kernel<<<NB*64, 128, 0, stream>>>(xin, partial);
  finalize_head_kernel<<<NB, 512, 0, stream>>>(partial, roW, rob, outp);
}

// Round 5
// 532.110 us; speedup vs baseline: 1.1024x; 1.1024x over previous
//
#include <hip/hip_runtime.h>
#include <stdint.h>
#include <math.h>

#pragma clang fp contract(off)

#define NB 4
#define NN 1024
#define KNN 20
#define NT 10

// ---------------------------------------------------------------------------
// Graph build
// ---------------------------------------------------------------------------
__global__ __launch_bounds__(256) void graph_kernel(const float* __restrict__ pc,
        int* __restrict__ idx_out, float* __restrict__ w_out, float* __restrict__ s_out){
  int row = blockIdx.x;              // b*NN + i
  int b = row >> 10, i = row & (NN-1);
  int tid = threadIdx.x;
  __shared__ float d2s[NN];
  __shared__ unsigned long long red[256];
  __shared__ int   sel_idx[KNN];
  __shared__ float sel_d2[KNN];
  const float* pb = pc + (size_t)b*NN*3;
  float xi = pb[i*3+0], yi = pb[i*3+1], zi = pb[i*3+2];
  for (int j=tid; j<NN; j+=256){
    float dx = xi - pb[j*3+0];
    float dy = yi - pb[j*3+1];
    float dz = zi - pb[j*3+2];
    float d2 = dx*dx;
    d2 = d2 + dy*dy;
    d2 = d2 + dz*dz;
    if (j==i) d2 = d2 + 1e9f;
    d2s[j] = d2;
  }
  __syncthreads();
  for (int k=0;k<KNN;k++){
    unsigned long long best = 0xffffffffffffffffull;
    for (int j=tid;j<NN;j+=256){
      unsigned long long key = ((unsigned long long)__float_as_uint(d2s[j])<<32) | (unsigned int)j;
      if (key < best) best = key;
    }
    red[tid] = best;
    __syncthreads();
    for (int off=128; off>0; off>>=1){
      if (tid < off){ if (red[tid+off] < red[tid]) red[tid] = red[tid+off]; }
      __syncthreads();
    }
    if (tid==0){
      unsigned long long bk = red[0];
      int bj = (int)(bk & 0xffffffffu);
      sel_idx[k] = bj;
      sel_d2[k]  = __uint_as_float((unsigned int)(bk >> 32));
      d2s[bj] = __uint_as_float(0x7f800000u);
    }
    __syncthreads();
  }
  if (tid==0){
    float dist[KNN]; float dsum = 0.0f;
    for (int k=0;k<KNN;k++){ dist[k] = sqrtf(fmaxf(sel_d2[k], 1e-12f)); dsum = dsum + dist[k]; }
    float sigma = dsum / 20.0f;
    sigma = 1.0f * sigma + 1e-6f;
    float s2 = sigma * sigma;
    float wv[KNN]; float wsum = 0.0f;
    for (int k=0;k<KNN;k++){
      float ds = dist[k]*dist[k];
      wv[k] = expf((-ds)/s2);
      wsum = wsum + wv[k];
    }
    float denom = wsum + 1e-6f;
    for (int k=0;k<KNN;k++){
      w_out[(size_t)row*KNN+k]  = wv[k] / denom;
      idx_out[(size_t)row*KNN+k] = sel_idx[k];
    }
    s_out[row] = 1.0f * sigma;
  }
}

// ---------------------------------------------------------------------------
// Encoder
// ---------------------------------------------------------------------------
__global__ void enc_kernel(const float* __restrict__ pc, const float* __restrict__ W,
                           const float* __restrict__ bias, float* __restrict__ rates){
  int id = blockIdx.x*blockDim.x + threadIdx.x;
  if (id >= NB*NN*64) return;
  int f = id & 63; int bn = id >> 6;
  float p0 = pc[bn*3+0], p1 = pc[bn*3+1], p2 = pc[bn*3+2];
  float acc = fmaf(p0, W[0*64+f], 0.0f);
  acc = fmaf(p1, W[1*64+f], acc);
  acc = fmaf(p2, W[2*64+f], acc);
  acc = acc + bias[f];
  acc = fmaxf(acc, 0.0f);
  acc = fminf(fmaxf(acc, 0.0f), 1.0f);
  rates[id] = acc;
}

// ---------------------------------------------------------------------------
// Poisson encoding (JAX threefry2x32, key (0,42))
// ---------------------------------------------------------------------------
__device__ __forceinline__ uint32_t rotl32(uint32_t x, uint32_t r){ return (x<<r) | (x>>(32u-r)); }

__global__ void poisson_kernel(const float* __restrict__ rates, uint8_t* __restrict__ out){
  const uint32_t H = (uint32_t)(NB*NT*NN*64) / 2u;
  uint32_t i = blockIdx.x*blockDim.x + threadIdx.x;
  if (i >= H) return;
  const uint32_t ks0 = 0u, ks1 = 42u;
  const uint32_t ks2 = ks0 ^ ks1 ^ 0x1BD11BDAu;
  uint32_t x0 = i + ks0;
  uint32_t x1 = (i + H) + ks1;
#define TF4(a,b,c,d) \
  x0 += x1; x1 = rotl32(x1,a); x1 ^= x0; \
  x0 += x1; x1 = rotl32(x1,b); x1 ^= x0; \
  x0 += x1; x1 = rotl32(x1,c); x1 ^= x0; \
  x0 += x1; x1 = rotl32(x1,d); x1 ^= x0;
  TF4(13u,15u,26u,6u)  x0 += ks1; x1 += ks2 + 1u;
  TF4(17u,29u,16u,24u) x0 += ks2; x1 += ks0 + 2u;
  TF4(13u,15u,26u,6u)  x0 += ks0; x1 += ks1 + 3u;
  TF4(17u,29u,16u,24u) x0 += ks1; x1 += ks2 + 4u;
  TF4(13u,15u,26u,6u)  x0 += ks2; x1 += ks0 + 5u;
#undef TF4
  {
    uint32_t m = i;
    float u = __uint_as_float((x0 >> 9) | 0x3f800000u) - 1.0f;
    uint32_t f = m & 63u, n = (m >> 6) & (NN-1);
    uint32_t bt = m >> 16; uint32_t b = bt / NT;
    float rate = rates[(((size_t)b<<10) + n)*64 + f];
    out[m] = (u < rate) ? (uint8_t)1 : (uint8_t)0;
  }
  {
    uint32_t m = i + H;
    float u = __uint_as_float((x1 >> 9) | 0x3f800000u) - 1.0f;
    uint32_t f = m & 63u, n = (m >> 6) & (NN-1);
    uint32_t bt = m >> 16; uint32_t b = bt / NT;
    float rate = rates[(((size_t)b<<10) + n)*64 + f];
    out[m] = (u < rate) ? (uint8_t)1 : (uint8_t)0;
  }
}

// ---------------------------------------------------------------------------
// lap1 (vectorized): 4 f-columns per thread, uchar4 gathers.
// t1 = s*(x - sum_k w_k x[idx_k]); fma chain over k ascending (bit-identical).
// ---------------------------------------------------------------------------
template<int F>
__global__ __launch_bounds__(256) void lap1_kernel3(const uint8_t* __restrict__ x,
        const int* __restrict__ idx, const float* __restrict__ w, const float* __restrict__ s,
        float* __restrict__ t1, int t0){
  constexpr int TPN = F / 4;                 // threads per node
  constexpr int R   = 256 / TPN;             // nodes per block
  int tid = threadIdx.x;
  int rsub = tid / TPN;
  int f4 = tid % TPN;
  int row = blockIdx.x * R + rsub;           // over M = NB*NN*tc
  int bn = row % (NB*NN); int tt = row / (NB*NN);
  int b = bn >> 10; int n = bn & (NN-1); int t = t0 + tt;
  __shared__ int   nidx[R][KNN];
  __shared__ float nw[R][KNN];
  __shared__ float sv[R];
  int bn0 = (blockIdx.x * R) % (NB*NN);
  for (int e=tid; e<R*KNN; e+=256){
    int r = e / KNN, k = e % KNN;
    nidx[r][k] = idx[(size_t)(bn0+r)*KNN+k];
    nw[r][k]   = w[(size_t)(bn0+r)*KNN+k];
  }
  for (int e=tid; e<R; e+=256) sv[e] = s[bn0+e];
  __syncthreads();
  const uint8_t* xb = x + ((size_t)(b*NT + t)*NN)*F;
  float a0=0.f,a1=0.f,a2=0.f,a3=0.f;
  for (int k=0;k<KNN;k++){
    float wk = nw[rsub][k];
    uchar4 u = *(const uchar4*)(xb + (size_t)nidx[rsub][k]*F + f4*4);
    a0 = fmaf(wk, (float)u.x, a0);
    a1 = fmaf(wk, (float)u.y, a1);
    a2 = fmaf(wk, (float)u.z, a2);
    a3 = fmaf(wk, (float)u.w, a3);
  }
  uchar4 ux = *(const uchar4*)(xb + (size_t)n*F + f4*4);
  float sl = sv[rsub];
  float4 o;
  o.x = sl * ((float)ux.x - a0);
  o.y = sl * ((float)ux.y - a1);
  o.z = sl * ((float)ux.z - a2);
  o.w = sl * ((float)ux.w - a3);
  *(float4*)(t1 + (size_t)row*F + f4*4) = o;
}

// ---------------------------------------------------------------------------
// lap2 (vectorized): t2 = 2*(s*(t1 - sum_k w_k t1[idx_k])) - x
// ---------------------------------------------------------------------------
template<int F>
__global__ __launch_bounds__(256) void lap2_kernel3(const uint8_t* __restrict__ x,
        const float* __restrict__ t1, const int* __restrict__ idx, const float* __restrict__ w,
        const float* __restrict__ s, float* __restrict__ t2, int t0){
  constexpr int TPN = F / 4;
  constexpr int R   = 256 / TPN;
  int tid = threadIdx.x;
  int rsub = tid / TPN;
  int f4 = tid % TPN;
  int row = blockIdx.x * R + rsub;
  int bn = row % (NB*NN); int tt = row / (NB*NN);
  int b = bn >> 10; int n = bn & (NN-1); int t = t0 + tt;
  __shared__ int   nidx[R][KNN];
  __shared__ float nw[R][KNN];
  __shared__ float sv[R];
  int bn0 = (blockIdx.x * R) % (NB*NN);
  for (int e=tid; e<R*KNN; e+=256){
    int r = e / KNN, k = e % KNN;
    nidx[r][k] = idx[(size_t)(bn0+r)*KNN+k];
    nw[r][k]   = w[(size_t)(bn0+r)*KNN+k];
  }
  for (int e=tid; e<R; e+=256) sv[e] = s[bn0+e];
  __syncthreads();
  const float* t1b = t1 + ((size_t)tt*(NB*NN) + (size_t)b*NN)*F;
  float a0=0.f,a1=0.f,a2=0.f,a3=0.f;
  for (int k=0;k<KNN;k++){
    float wk = nw[rsub][k];
    float4 v = *(const float4*)(t1b + (size_t)nidx[rsub][k]*F + f4*4);
    a0 = fmaf(wk, v.x, a0);
    a1 = fmaf(wk, v.y, a1);
    a2 = fmaf(wk, v.z, a2);
    a3 = fmaf(wk, v.w, a3);
  }
  float4 tv = *(const float4*)(t1 + (size_t)row*F + f4*4);
  uchar4 ux = *(const uchar4*)(x + ((size_t)(b*NT + t)*NN + n)*F + f4*4);
  float sl = sv[rsub];
  float4 o;
  o.x = 2.0f * (sl * (tv.x - a0)) - (float)ux.x;
  o.y = 2.0f * (sl * (tv.y - a1)) - (float)ux.y;
  o.z = 2.0f * (sl * (tv.z - a2)) - (float)ux.z;
  o.w = 2.0f * (sl * (tv.w - a3)) - (float)ux.w;
  *(float4*)(t2 + (size_t)row*F + f4*4) = o;
}

// ---------------------------------------------------------------------------
// Chebyshev conv GEMM v3: BM=64 (grid back to 1280 blocks for l2/l3),
// conflict-free half-tile LDS reads (broadcast A, 2-way W), k-chain order
// unchanged (s-major, f ascending) -> bit-identical outputs.
// ---------------------------------------------------------------------------
template<int F, int G, int BN, int TN>
__global__ __launch_bounds__(256) void conv_gemm3_kernel(const uint8_t* __restrict__ x,
        const float* __restrict__ t1, const float* __restrict__ t2,
        const float* __restrict__ W, float* __restrict__ abuf, int t0){
  constexpr int BM = 64, BK = 16, TM = 4;
  constexpr int NTX = BN / TN;               // 16
  constexpr int NTY = 256 / NTX;             // 16
  static_assert(NTY * TM == BM, "tile mismatch");
  constexpr int LDA = BM + 4;                // 68
  constexpr int LDB = BN + 4;                // 68 / 132
  __shared__ float As[BK * LDA];
  __shared__ float Ws[BK * LDB];

  const int tid = threadIdx.x;
  const int tx = tid % NTX, ty = tid / NTX;
  const int row0 = blockIdx.x * BM;
  const int g0 = blockIdx.y * BN;

  // A-load mapping: each thread loads 4 consecutive k for one row
  const int arow = tid >> 2;                 // 0..63
  const int akg  = (tid & 3) * 4;            // 0,4,8,12
  const int grow = row0 + arow;
  const int bn_a = grow % (NB*NN);
  const int tt_a = grow / (NB*NN);
  const int b_a = bn_a >> 10, n_a = bn_a & (NN-1);
  const uint8_t* xrow  = x  + ((size_t)(b_a*NT + t0 + tt_a)*NN + n_a)*F;
  const float*   t1row = t1 + (size_t)grow * F;
  const float*   t2row = t2 + (size_t)grow * F;

  float acc[TM][TN];
  #pragma unroll
  for (int r=0;r<TM;r++)
    #pragma unroll
    for (int c=0;c<TN;c++) acc[r][c] = 0.0f;

  for (int s = 0; s < 3; ++s){
    for (int f0 = 0; f0 < F; f0 += BK){
      // --- stage A chunk: rows of [x|t1|t2] ---
      if (s == 0){
        uchar4 u = *(const uchar4*)(xrow + f0 + akg);
        As[(akg+0)*LDA + arow] = (float)u.x;
        As[(akg+1)*LDA + arow] = (float)u.y;
        As[(akg+2)*LDA + arow] = (float)u.z;
        As[(akg+3)*LDA + arow] = (float)u.w;
      } else {
        const float* src = ((s==1) ? t1row : t2row) + f0 + akg;
        float4 v = *(const float4*)src;
        As[(akg+0)*LDA + arow] = v.x;
        As[(akg+1)*LDA + arow] = v.y;
        As[(akg+2)*LDA + arow] = v.z;
        As[(akg+3)*LDA + arow] = v.w;
      }
      // --- stage W chunk ---
      const float* Wsrc = W + ((size_t)(s*F + f0))*G + g0;
      #pragma unroll
      for (int e = 0; e < (BK*BN)/(256*4); ++e){
        int idx2 = tid + e*256;
        int wk = idx2 / (BN/4);
        int wg = (idx2 % (BN/4))*4;
        *(float4*)&Ws[wk*LDB + wg] = *(const float4*)(Wsrc + (size_t)wk*G + wg);
      }
      __syncthreads();
      // --- compute ---
      #pragma unroll
      for (int k = 0; k < BK; ++k){
        float a[TM];
        *(float2*)&a[0] = *(const float2*)&As[k*LDA + ty*2];
        *(float2*)&a[2] = *(const float2*)&As[k*LDA + BM/2 + ty*2];
        float wv[TN];
        if constexpr (TN == 8){
          *(float4*)&wv[0] = *(const float4*)&Ws[k*LDB + tx*4];
          *(float4*)&wv[4] = *(const float4*)&Ws[k*LDB + BN/2 + tx*4];
        } else {
          *(float2*)&wv[0] = *(const float2*)&Ws[k*LDB + tx*2];
          *(float2*)&wv[2] = *(const float2*)&Ws[k*LDB + BN/2 + tx*2];
        }
        #pragma unroll
        for (int r=0;r<TM;r++)
          #pragma unroll
          for (int c=0;c<TN;c++)
            acc[r][c] = fmaf(a[r], wv[c], acc[r][c]);
      }
      __syncthreads();
    }
  }
  // epilogue: raw GEMM result (bias added in LIF, preserving order)
  #pragma unroll
  for (int rg=0; rg<2; ++rg){
    #pragma unroll
    for (int r=0; r<TM/2; ++r){
      float* dst = abuf + (size_t)(row0 + rg*(BM/2) + ty*2 + r)*G + g0;
      if constexpr (TN == 8){
        *(float4*)(dst + tx*4)        = *(float4*)&acc[rg*2+r][0];
        *(float4*)(dst + BN/2 + tx*4) = *(float4*)&acc[rg*2+r][4];
      } else {
        *(float2*)(dst + tx*2)        = *(float2*)&acc[rg*2+r][0];
        *(float2*)(dst + BN/2 + tx*2) = *(float2*)&acc[rg*2+r][2];
      }
    }
  }
}

// ---------------------------------------------------------------------------
// LIF scan: bias added here in reference order: a = gemm + b; v = decay*v + a
// ---------------------------------------------------------------------------
__global__ void lif_kernel(const float* __restrict__ abuf, const float* __restrict__ bias,
        float* __restrict__ vbuf, uint8_t* __restrict__ out, int t0, int tc, int G, float decay){
  int id = blockIdx.x*blockDim.x + threadIdx.x;
  if (id >= NB*NN*G) return;
  int g = id % G;
  int bn = id / G;
  int b = bn >> 10, n = bn & (NN-1);
  float v = (t0 == 0) ? 0.0f : vbuf[id];
  float bg = bias[g];
  for (int tt=0; tt<tc; ++tt){
    float a = abuf[((size_t)tt*(NB*NN) + bn)*G + g] + bg;
    float vn = decay * v + a;
    float sp  = ((vn - 1.0f) >= 0.0f) ? 1.0f : 0.0f;
    float snk = ((-1.0f - vn) >= 0.0f) ? 1.0f : 0.0f;
    vn = vn - sp * 1.0f;
    vn = vn - snk * (-1.0f);
    v = vn;
    uint8_t* ob = out + ((size_t)(b*NT + t0 + tt)*NN + n)*((size_t)2*G);
    ob[g]   = (uint8_t)sp;
    ob[G+g] = (uint8_t)snk;
  }
  if (t0 + tc < NT) vbuf[id] = v;
}

// ---------------------------------------------------------------------------
// Pool stage 1: integer spike counts (exact, order-independent)
// ---------------------------------------------------------------------------
__global__ void pool_partial_kernel(const uint8_t* __restrict__ sp, uint32_t* __restrict__ partial){
  int b = blockIdx.x >> 6;
  int chunk = blockIdx.x & 63;
  int n0 = chunk * 16;
  int u = threadIdx.x;                      // 0..127
  uint32_t c0=0,c1=0,c2=0,c3=0;
  for (int t=0;t<NT;t++){
    for (int n=0;n<16;n++){
      const uint32_t* rowp = (const uint32_t*)(sp + ((size_t)(b*NT+t)*NN + n0+n)*512);
      uint32_t wv = rowp[u];
      c0 += wv & 0xffu;
      c1 += (wv >> 8) & 0xffu;
      c2 += (wv >> 16) & 0xffu;
      c3 += wv >> 24;
    }
  }
  uint32_t* op = partial + (size_t)blockIdx.x*512 + u*4;
  op[0]=c0; op[1]=c1; op[2]=c2; op[3]=c3;
}

__global__ __launch_bounds__(512) void finalize_head_kernel(const uint32_t* __restrict__ partial,
        const float* __restrict__ roW, const float* __restrict__ rob, float* __restrict__ out){
  int b = blockIdx.x;
  int f = threadIdx.x;
  __shared__ float pooled[512];
  uint32_t cnt = 0;
  for (int ch=0; ch<64; ch++)
    cnt += partial[((size_t)(b*64+ch))*512 + f];
  pooled[f] = (float)cnt / 10.0f / 1024.0f;
  __syncthreads();
  if (f < 40){
    float acc = 0.0f;
    for (int k=0;k<512;k++)
      acc = fmaf(pooled[k], roW[k*40+f], acc);
    out[b*40 + f] = acc + rob[f];
  }
}

// ---------------------------------------------------------------------------
extern "C" void kernel_launch(void* const* d_in, const int* in_sizes, int n_in,
                              void* d_out, int out_size, void* d_ws, size_t ws_size,
                              hipStream_t stream) {
  const float* pc   = (const float*)d_in[0];
  const float* encW = (const float*)d_in[1];
  const float* encB = (const float*)d_in[2];
  const float* W0   = (const float*)d_in[3];
  const float* b0   = (const float*)d_in[4];
  const float* W1   = (const float*)d_in[5];
  const float* b1   = (const float*)d_in[6];
  const float* W2   = (const float*)d_in[7];
  const float* b2   = (const float*)d_in[8];
  const float* roW  = (const float*)d_in[9];
  const float* rob  = (const float*)d_in[10];
  float* outp = (float*)d_out;

  char* p = (char*)d_ws;
  auto alloc = [&](size_t bytes)->char*{
    char* r = p; p += (bytes + 255) & ~(size_t)255; return r;
  };
  int*      idxb   = (int*)     alloc((size_t)NB*NN*KNN*4);
  float*    wb     = (float*)   alloc((size_t)NB*NN*KNN*4);
  float*    sb     = (float*)   alloc((size_t)NB*NN*4);
  float*    rates  = (float*)   alloc((size_t)NB*NN*64*4);
  float*    vbuf   = (float*)   alloc((size_t)NB*NN*256*4);
  uint32_t* partial= (uint32_t*)alloc((size_t)NB*64*512*4);
  uint8_t*  bufA   = (uint8_t*) alloc((size_t)NB*NT*NN*512);
  uint8_t*  bufB   = (uint8_t*) alloc((size_t)NB*NT*NN*512);

  // timestep chunking: t1 + t2 + abuf per timestep (worst case F=256)
  size_t used = (size_t)(p - (char*)d_ws);
  size_t per_t = (size_t)NB*NN*256*4*3;
  int TC = 1;
  if (ws_size > used + per_t){
    size_t tcc = (ws_size - used) / per_t;
    TC = (tcc >= NT) ? NT : (int)tcc;
    if (TC < 1) TC = 1;
  }
  float* t1b  = (float*)alloc((size_t)NB*(size_t)TC*NN*256*4);
  float* t2b  = (float*)alloc((size_t)NB*(size_t)TC*NN*256*4);
  float* abuf = (float*)alloc((size_t)NB*(size_t)TC*NN*256*4);

  graph_kernel<<<NB*NN, 256, 0, stream>>>(pc, idxb, wb, sb);
  enc_kernel<<<(NB*NN*64 + 255)/256, 256, 0, stream>>>(pc, encW, encB, rates);
  {
    const uint32_t H = (uint32_t)(NB*NT*NN*64) / 2u;
    poisson_kernel<<<(H + 255)/256, 256, 0, stream>>>(rates, bufA);
  }

  float decay = expf(-1.0f / 20.0f);

  uint8_t* xin  = bufA;
  uint8_t* xout = bufB;
  for (int l=0; l<3; l++){
    int G = (l==0)?64:(l==1)?128:256;
    const float* Wc = (l==0)?W0:(l==1)?W1:W2;
    const float* bc = (l==0)?b0:(l==1)?b1:b2;
    for (int t0=0; t0<NT; t0+=TC){
      int tc = (NT - t0 < TC) ? (NT - t0) : TC;
      int M = NB*NN*tc;
      if (l==0){
        lap1_kernel3<64><<<M/16, 256, 0, stream>>>(xin, idxb, wb, sb, t1b, t0);
        lap2_kernel3<64><<<M/16, 256, 0, stream>>>(xin, t1b, idxb, wb, sb, t2b, t0);
        dim3 grid(M/64, 1);
        conv_gemm3_kernel<64,64,64,4><<<grid, 256, 0, stream>>>(xin, t1b, t2b, Wc, abuf, t0);
      } else if (l==1){
        lap1_kernel3<128><<<M/8, 256, 0, stream>>>(xin, idxb, wb, sb, t1b, t0);
        lap2_kernel3<128><<<M/8, 256, 0, stream>>>(xin, t1b, idxb, wb, sb, t2b, t0);
        dim3 grid(M/64, 2);
        conv_gemm3_kernel<128,128,64,4><<<grid, 256, 0, stream>>>(xin, t1b, t2b, Wc, abuf, t0);
      } else {
        lap1_kernel3<256><<<M/4, 256, 0, stream>>>(xin, idxb, wb, sb, t1b, t0);
        lap2_kernel3<256><<<M/4, 256, 0, stream>>>(xin, t1b, idxb, wb, sb, t2b, t0);
        dim3 grid(M/64, 2);
        conv_gemm3_kernel<256,256,128,8><<<grid, 256, 0, stream>>>(xin, t1b, t2b, Wc, abuf, t0);
      }
      lif_kernel<<<(NB*NN*G + 255)/256, 256, 0, stream>>>(abuf, bc, vbuf, xout, t0, tc, G, decay);
    }
    uint8_t* tmp = xin; xin = xout; xout = tmp;
  }

  pool_partial_kernel<<<NB*64, 128, 0, stream>>>(xin, partial);
  finalize_head_kernel<<<NB, 512, 0, stream>>>(partial, roW, rob, outp);
}